// Round 9
// baseline (758.630 us; speedup 1.0000x reference)
//
#include <hip/hip_runtime.h>
#include <math.h>

#define EQCAP 2048
#define PI_D 3.141592653589793

// ---------- helpers ----------
__device__ inline void wred_max4(float& a, float& b, float& c, float& d) {
    #pragma unroll
    for (int o = 32; o; o >>= 1) {
        a = fmaxf(a, __shfl_xor(a, o));
        b = fmaxf(b, __shfl_xor(b, o));
        c = fmaxf(c, __shfl_xor(c, o));
        d = fmaxf(d, __shfl_xor(d, o));
    }
}
__device__ inline void wred_sum4(float& a, float& b, float& c, float& d) {
    #pragma unroll
    for (int o = 32; o; o >>= 1) {
        a += __shfl_xor(a, o);
        b += __shfl_xor(b, o);
        c += __shfl_xor(c, o);
        d += __shfl_xor(d, o);
    }
}
__device__ inline void wred_sum2(float& a, float& b) {
    #pragma unroll
    for (int o = 32; o; o >>= 1) {
        a += __shfl_xor(a, o);
        b += __shfl_xor(b, o);
    }
}
__device__ inline unsigned fflip(float f) {
    unsigned b = __float_as_uint(f);
    return (b & 0x80000000u) ? ~b : (b | 0x80000000u);
}

// ---------- kernel 0: zero the scalar workspace slots ----------
__global__ void k_init(double* acc, int* count, unsigned* gmax_u, int* eqc) {
    if (threadIdx.x == 0) {
        *acc = 0.0; *count = 0;
        gmax_u[0] = 0u; gmax_u[1] = 0u;
        eqc[0] = 0; eqc[1] = 0;
    }
}

// ---------- kernel 1: per-row KL loss, BOTH axes per wave (latency-bound fix) ----------
// R8 PMC: VALUBusy 29%, hbm 19%, occ 56% -> latency-bound (4 loads + serial
// shfl-reduction chain per wave). This version: one wave = row m for x AND y
// axes -> 8 loads in flight, 4 interleaved reduction chains (2x ILP).
// Epilogue folds old k_stats2: per-wave atomicMax gmax + conditional count.
__global__ __launch_bounds__(256, 4) void k_loss(
    const float* __restrict__ px, const float* __restrict__ py,
    const float* __restrict__ gx, const float* __restrict__ gy,
    const float* __restrict__ tw, float* __restrict__ lossbuf,
    int* __restrict__ count, unsigned* __restrict__ gmax_u, int M)
{
    int row  = (blockIdx.x * blockDim.x + threadIdx.x) >> 6;
    int lane = threadIdx.x & 63;
    if (row >= M) return;
    size_t base = (size_t)row * 512;
    const float4* x4 = reinterpret_cast<const float4*>(px + base);
    const float4* y4 = reinterpret_cast<const float4*>(py + base);
    const float4* u4 = reinterpret_cast<const float4*>(gx + base);
    const float4* v4 = reinterpret_cast<const float4*>(gy + base);
    float4 xA = x4[lane], xB = x4[lane + 64];
    float4 uA = u4[lane], uB = u4[lane + 64];
    float4 yA = y4[lane], yB = y4[lane + 64];
    float4 vA = v4[lane], vB = v4[lane + 64];

    float pX[8] = {xA.x, xA.y, xA.z, xA.w, xB.x, xB.y, xB.z, xB.w};
    float gX[8] = {uA.x, uA.y, uA.z, uA.w, uB.x, uB.y, uB.z, uB.w};
    float pY[8] = {yA.x, yA.y, yA.z, yA.w, yB.x, yB.y, yB.z, yB.w};
    float gY[8] = {vA.x, vA.y, vA.z, vA.w, vB.x, vB.y, vB.z, vB.w};

    float mpX = -INFINITY, mgX = -INFINITY, mpY = -INFINITY, mgY = -INFINITY;
    #pragma unroll
    for (int i = 0; i < 8; i++) {
        mpX = fmaxf(mpX, pX[i]); mgX = fmaxf(mgX, gX[i]);
        mpY = fmaxf(mpY, pY[i]); mgY = fmaxf(mgY, gY[i]);
    }
    wred_max4(mpX, mgX, mpY, mgY);

    float sPX = 0.f, sGX = 0.f, sPY = 0.f, sGY = 0.f;
    #pragma unroll
    for (int i = 0; i < 8; i++) {
        sPX += __expf(pX[i] - mpX); sGX += __expf(gX[i] - mgX);
        sPY += __expf(pY[i] - mpY); sGY += __expf(gY[i] - mgY);
    }
    wred_sum4(sPX, sGX, sPY, sGY);
    float lPX = __logf(sPX), lGX = __logf(sGX);
    float lPY = __logf(sPY), lGY = __logf(sGY);

    float aX = 0.f, aY = 0.f;
    #pragma unroll
    for (int i = 0; i < 8; i++) {
        float lsgX = (gX[i] - mgX) - lGX;   // log_softmax(gt_x)
        float lspX = (pX[i] - mpX) - lPX;   // log_softmax(pred_x)
        aX += __expf(lsgX) * (lsgX - lspX);
        float lsgY = (gY[i] - mgY) - lGY;
        float lspY = (pY[i] - mpY) - lPY;
        aY += __expf(lsgY) * (lsgY - lspY);
    }
    wred_sum2(aX, aY);

    if (lane == 0) {
        float lx = aX * (1.0f / 512.0f);
        float ly = aY * (1.0f / 512.0f);
        lossbuf[row]     = lx;
        lossbuf[M + row] = ly;
        atomicMax(&gmax_u[0], fflip(lx));
        atomicMax(&gmax_u[1], fflip(ly));
        if (tw[row] != 0.0f) atomicAdd(count, 1);
    }
}

// ---------- kernel 3: radix select — stage keys in LDS once, 4 passes from LDS ----------
// 1024 threads/block, one block per axis. Global data is touched exactly once.
__global__ __launch_bounds__(1024) void k_select(
    const float* __restrict__ tw, const float* __restrict__ lossbuf,
    const int* __restrict__ count, const unsigned* __restrict__ gmax_u,
    const int* __restrict__ ep,
    int* __restrict__ ki, unsigned* __restrict__ thr_u, int* __restrict__ cless, int M)
{
    extern __shared__ unsigned keys[];      // M unsigned keys (68 KB for M=17408)
    int ax = blockIdx.x;
    int tid = threadIdx.x, lane = tid & 63, wv = tid >> 6;
    __shared__ int hist[256];
    __shared__ unsigned s_pref;
    __shared__ int s_kr, s_cl;
    __shared__ int wsum[4];

    if (tid == 0) {
        int c = *count;
        double cur = fmin(fmax((double)(ep[0] - 210), 0.0), 30.0);
        double r = 0.5 * (cos(PI_D * cur / 30.0) + 1.0);
        r = fmin(fmax(r, 0.8), 1.0);
        int k = (int)((double)c * r);    // truncation matches Python int()
        s_kr = k; s_pref = 0u; s_cl = 0;
        if (ax == 0) *ki = k;
    }

    // stage keys: independent loads, fully pipelined; one global pass total
    unsigned gmu = gmax_u[ax];
    const float* lb = lossbuf + (size_t)ax * M;
    for (int j = tid; j < M; j += 1024) {
        float t = tw[j];
        float l = lb[j];
        keys[j] = (t > 0.f) ? fflip(l) : gmu;
    }
    __syncthreads();

    int k0 = s_kr;
    if (k0 <= 0) { if (tid == 0) { thr_u[ax] = 0u; cless[ax] = 0; } return; }

    const unsigned mhi[4] = {0x00000000u, 0xFF000000u, 0xFFFF0000u, 0xFFFFFF00u};

    for (int pass = 0; pass < 4; ++pass) {
        int shift = 24 - 8 * pass;
        if (tid < 256) hist[tid] = 0;
        __syncthreads();
        unsigned m = mhi[pass];
        unsigned pref = s_pref;
        for (int j = tid; j < M; j += 1024) {
            unsigned v = keys[j];
            if ((v & m) == (pref & m)) atomicAdd(&hist[(v >> shift) & 255], 1);
        }
        __syncthreads();
        int kr = s_kr;                 // read before anyone can write it
        int h = (tid < 256) ? hist[tid] : 0;
        int inc = h;
        #pragma unroll
        for (int o = 1; o < 64; o <<= 1) {
            int n = __shfl_up(inc, o);
            if (lane >= o) inc += n;
        }
        if (lane == 63 && wv < 4) wsum[wv] = inc;
        __syncthreads();               // separates s_kr read from the write below
        if (tid < 256) {
            int off = 0;
            #pragma unroll
            for (int w = 0; w < 4; w++) if (w < wv) off += wsum[w];
            int incl = inc + off, excl = incl - h;
            if (excl < kr && incl >= kr) { // exactly one thread
                s_pref |= ((unsigned)tid) << shift;
                s_kr = kr - excl;
                s_cl += excl;
            }
        }
        __syncthreads();
    }
    if (tid == 0) { thr_u[ax] = s_pref; cless[ax] = s_cl; }
}

// ---------- kernel 4: weights + masked dot partials ----------
__global__ __launch_bounds__(256) void k_weight(
    const float* __restrict__ tw, const int* __restrict__ ul,
    const float* __restrict__ lossbuf, const unsigned* __restrict__ gmax_u,
    float* __restrict__ outw, const int* __restrict__ ki,
    const unsigned* __restrict__ thr_u, int* __restrict__ eqc,
    int* __restrict__ eqlist, double* __restrict__ acc, int M, int Kj)
{
    int ax = blockIdx.y;
    int m = blockIdx.x * blockDim.x + threadIdx.x;
    double contrib = 0.0;
    if (m < M) {
        int k = *ki;
        float mask = 0.f;
        unsigned v = (tw[m] > 0.f) ? fflip(lossbuf[(size_t)ax * M + m]) : gmax_u[ax];
        unsigned t = thr_u[ax];
        if (k > 0) {
            if (v < t) mask = 1.f;
            else if (v == t) {
                int pos = atomicAdd(&eqc[ax], 1);
                if (pos < EQCAP) eqlist[ax * EQCAP + pos] = m;
            }
        }
        float wr = (ul[m / Kj] == 0) ? tw[m] : 0.f;   // weight_real
        float wall = 2.f * wr + mask;
        outw[(size_t)ax * M + m] = wall;
        contrib = (double)lossbuf[(size_t)ax * M + m] * (double)wall;
    }
    #pragma unroll
    for (int o = 32; o; o >>= 1) contrib += __shfl_xor(contrib, o);
    __shared__ double s_c[4];
    int lane = threadIdx.x & 63, wv = threadIdx.x >> 6;
    if (lane == 0) s_c[wv] = contrib;
    __syncthreads();
    if (threadIdx.x == 0) atomicAdd(acc, s_c[0] + s_c[1] + s_c[2] + s_c[3]);
}

// ---------- kernel 5: tie fixup (lowest-index semantics) + final scalar ----------
__global__ __launch_bounds__(256) void k_fix(
    float* __restrict__ outw, float* __restrict__ out0,
    const float* __restrict__ lossbuf, const int* __restrict__ ki,
    const int* __restrict__ cless, const int* __restrict__ eqc,
    const int* __restrict__ eqlist, const double* __restrict__ acc, int M, int Kj)
{
    __shared__ double s_c[4];
    int tid = threadIdx.x;
    double extra = 0.0;
    for (int ax = 0; ax < 2; ++ax) {
        int k = *ki;
        int ec = eqc[ax]; if (ec > EQCAP) ec = EQCAP;
        int need = (k > 0) ? (k - cless[ax]) : 0;
        if (need < 0) need = 0;
        if (need > ec) need = ec;
        if (need == ec) {
            for (int i = tid; i < ec; i += 256) {
                int m = eqlist[ax * EQCAP + i];
                outw[(size_t)ax * M + m] += 1.f;
                extra += (double)lossbuf[(size_t)ax * M + m];
            }
        } else if (tid == 0) {
            // pick `need` lowest indices among equals (top_k tie semantics)
            int last = -1;
            for (int s = 0; s < need; ++s) {
                int best = 0x7fffffff;
                for (int i = 0; i < ec; i++) {
                    int v = eqlist[ax * EQCAP + i];
                    if (v > last && v < best) best = v;
                }
                last = best;
                outw[(size_t)ax * M + best] += 1.f;
                extra += (double)lossbuf[(size_t)ax * M + best];
            }
        }
        __syncthreads();
    }
    #pragma unroll
    for (int o = 32; o; o >>= 1) extra += __shfl_xor(extra, o);
    int lane = tid & 63, wv = tid >> 6;
    if (lane == 0) s_c[wv] = extra;
    __syncthreads();
    if (tid == 0)
        out0[0] = (float)((acc[0] + s_c[0] + s_c[1] + s_c[2] + s_c[3]) / (double)Kj);
}

extern "C" void kernel_launch(void* const* d_in, const int* in_sizes, int n_in,
                              void* d_out, int out_size, void* d_ws, size_t ws_size,
                              hipStream_t stream)
{
    const float* px = (const float*)d_in[0];
    const float* py = (const float*)d_in[1];
    const float* gx = (const float*)d_in[2];
    const float* gy = (const float*)d_in[3];
    const float* tw = (const float*)d_in[4];
    const int*   ul = (const int*)d_in[5];
    const int*   ep = (const int*)d_in[6];

    int M  = in_sizes[4];        // N*K = 17408
    int N  = in_sizes[5];        // 1024
    int Kj = M / N;              // 17

    float* out  = (float*)d_out;
    float* out0 = out;           // scalar loss
    float* outw = out + 1;       // [2*M] weights (x then y)

    char* ws = (char*)d_ws;
    double*   acc     = (double*)(ws + 0);
    int*      ki      = (int*)(ws + 8);
    int*      count   = (int*)(ws + 12);
    unsigned* gmax_u  = (unsigned*)(ws + 16);
    unsigned* thr_u   = (unsigned*)(ws + 24);
    int*      cless   = (int*)(ws + 32);
    int*      eqc     = (int*)(ws + 40);
    float*    lossbuf = (float*)(ws + 64);
    int*      eqlist  = (int*)(ws + 64 + (size_t)8 * M);

    k_init<<<1, 64, 0, stream>>>(acc, count, gmax_u, eqc);

    // per-row losses: one wave handles row m for BOTH axes; stats fused
    int blocks = (M * 64 + 255) / 256;
    k_loss<<<blocks, 256, 0, stream>>>(px, py, gx, gy, tw, lossbuf,
                                       count, gmax_u, M);

    // radix select: stage keys in LDS (dynamic, M*4 bytes), 4 passes from LDS
    size_t lds_bytes = (size_t)M * sizeof(unsigned);
    k_select<<<2, 1024, lds_bytes, stream>>>(tw, lossbuf, count, gmax_u, ep,
                                             ki, thr_u, cless, M);

    // weights + dot partials
    dim3 g4((M + 255) / 256, 2);
    k_weight<<<g4, 256, 0, stream>>>(tw, ul, lossbuf, gmax_u, outw, ki, thr_u,
                                     eqc, eqlist, acc, M, Kj);

    // tie fixup + final scalar
    k_fix<<<1, 256, 0, stream>>>(outw, out0, lossbuf, ki, cless, eqc, eqlist, acc, M, Kj);
}

// Round 12
// 206.885 us; speedup vs baseline: 3.6669x; 3.6669x over previous
//
#include <hip/hip_runtime.h>
#include <math.h>

#define EQCAP 2048
#define PI_D 3.141592653589793

// ---------- helpers ----------
__device__ inline void wred_max4(float& a, float& b, float& c, float& d) {
    #pragma unroll
    for (int o = 32; o; o >>= 1) {
        a = fmaxf(a, __shfl_xor(a, o));
        b = fmaxf(b, __shfl_xor(b, o));
        c = fmaxf(c, __shfl_xor(c, o));
        d = fmaxf(d, __shfl_xor(d, o));
    }
}
__device__ inline void wred_sum4(float& a, float& b, float& c, float& d) {
    #pragma unroll
    for (int o = 32; o; o >>= 1) {
        a += __shfl_xor(a, o);
        b += __shfl_xor(b, o);
        c += __shfl_xor(c, o);
        d += __shfl_xor(d, o);
    }
}
__device__ inline void wred_sum2(float& a, float& b) {
    #pragma unroll
    for (int o = 32; o; o >>= 1) {
        a += __shfl_xor(a, o);
        b += __shfl_xor(b, o);
    }
}
__device__ inline unsigned fflip(float f) {
    unsigned b = __float_as_uint(f);
    return (b & 0x80000000u) ? ~b : (b | 0x80000000u);
}

// ---------- kernel 0: zero the scalar workspace slots ----------
__global__ void k_init(double* acc, int* count, unsigned* gmax_u, int* eqc) {
    if (threadIdx.x == 0) {
        *acc = 0.0; *count = 0;
        gmax_u[0] = 0u; gmax_u[1] = 0u;
        eqc[0] = 0; eqc[1] = 0;
    }
}

// ---------- kernel 1: per-row KL loss, BOTH axes per wave ----------
// R9 lesson: NO per-wave global atomics here (17k waves x 3 atomics on one
// cache line serialized -> 611us). Stats live in k_stats2 (block-reduced).
// Structure: one wave = row m for x AND y axes -> 8 indep float4 loads in
// flight, 4 interleaved shfl-reduction chains (2x ILP vs R8).
__global__ __launch_bounds__(256, 4) void k_loss(
    const float* __restrict__ px, const float* __restrict__ py,
    const float* __restrict__ gx, const float* __restrict__ gy,
    float* __restrict__ lossbuf, int M)
{
    int row  = (blockIdx.x * blockDim.x + threadIdx.x) >> 6;
    int lane = threadIdx.x & 63;
    if (row >= M) return;
    size_t base = (size_t)row * 512;
    const float4* x4 = reinterpret_cast<const float4*>(px + base);
    const float4* y4 = reinterpret_cast<const float4*>(py + base);
    const float4* u4 = reinterpret_cast<const float4*>(gx + base);
    const float4* v4 = reinterpret_cast<const float4*>(gy + base);
    float4 xA = x4[lane], xB = x4[lane + 64];
    float4 uA = u4[lane], uB = u4[lane + 64];
    float4 yA = y4[lane], yB = y4[lane + 64];
    float4 vA = v4[lane], vB = v4[lane + 64];

    float pX[8] = {xA.x, xA.y, xA.z, xA.w, xB.x, xB.y, xB.z, xB.w};
    float gX[8] = {uA.x, uA.y, uA.z, uA.w, uB.x, uB.y, uB.z, uB.w};
    float pY[8] = {yA.x, yA.y, yA.z, yA.w, yB.x, yB.y, yB.z, yB.w};
    float gY[8] = {vA.x, vA.y, vA.z, vA.w, vB.x, vB.y, vB.z, vB.w};

    float mpX = -INFINITY, mgX = -INFINITY, mpY = -INFINITY, mgY = -INFINITY;
    #pragma unroll
    for (int i = 0; i < 8; i++) {
        mpX = fmaxf(mpX, pX[i]); mgX = fmaxf(mgX, gX[i]);
        mpY = fmaxf(mpY, pY[i]); mgY = fmaxf(mgY, gY[i]);
    }
    wred_max4(mpX, mgX, mpY, mgY);

    float sPX = 0.f, sGX = 0.f, sPY = 0.f, sGY = 0.f;
    #pragma unroll
    for (int i = 0; i < 8; i++) {
        sPX += __expf(pX[i] - mpX); sGX += __expf(gX[i] - mgX);
        sPY += __expf(pY[i] - mpY); sGY += __expf(gY[i] - mgY);
    }
    wred_sum4(sPX, sGX, sPY, sGY);
    float lPX = __logf(sPX), lGX = __logf(sGX);
    float lPY = __logf(sPY), lGY = __logf(sGY);

    float aX = 0.f, aY = 0.f;
    #pragma unroll
    for (int i = 0; i < 8; i++) {
        float lsgX = (gX[i] - mgX) - lGX;   // log_softmax(gt_x)
        float lspX = (pX[i] - mpX) - lPX;   // log_softmax(pred_x)
        aX += __expf(lsgX) * (lsgX - lspX);
        float lsgY = (gY[i] - mgY) - lGY;
        float lspY = (pY[i] - mpY) - lPY;
        aY += __expf(lsgY) * (lsgY - lspY);
    }
    wred_sum2(aX, aY);

    if (lane == 0) {
        lossbuf[row]     = aX * (1.0f / 512.0f);
        lossbuf[M + row] = aY * (1.0f / 512.0f);
    }
}

// ---------- kernel 2: multi-block stats: count_nonzero(tw), per-axis max ----------
// 68 blocks, block-reduce then ONE atomicAdd + 2 atomicMax per block.
__global__ __launch_bounds__(256) void k_stats2(
    const float* __restrict__ tw, const float* __restrict__ lossbuf,
    int* __restrict__ count, unsigned* __restrict__ gmax_u, int M)
{
    int tid = threadIdx.x, lane = tid & 63, wv = tid >> 6;
    int j = blockIdx.x * 256 + tid;
    int c = 0; unsigned ux = 0u, uy = 0u;
    if (j < M) {
        c  = (tw[j] != 0.0f);
        ux = fflip(lossbuf[j]);
        uy = fflip(lossbuf[M + j]);
    }
    #pragma unroll
    for (int o = 32; o; o >>= 1) {
        c += __shfl_xor(c, o);
        ux = max(ux, (unsigned)__shfl_xor((int)ux, o));
        uy = max(uy, (unsigned)__shfl_xor((int)uy, o));
    }
    __shared__ int sc[4]; __shared__ unsigned sx[4], sy[4];
    if (lane == 0) { sc[wv] = c; sx[wv] = ux; sy[wv] = uy; }
    __syncthreads();
    if (tid == 0) {
        int cs = sc[0] + sc[1] + sc[2] + sc[3];
        unsigned xs = max(max(sx[0], sx[1]), max(sx[2], sx[3]));
        unsigned ys = max(max(sy[0], sy[1]), max(sy[2], sy[3]));
        if (cs) atomicAdd(count, cs);
        atomicMax(&gmax_u[0], xs);
        atomicMax(&gmax_u[1], ys);
    }
}

// ---------- kernel 3: radix select — stage keys in LDS once, 4 passes from LDS ----------
// 1024 threads/block, one block per axis. Global data is touched exactly once.
__global__ __launch_bounds__(1024) void k_select(
    const float* __restrict__ tw, const float* __restrict__ lossbuf,
    const int* __restrict__ count, const unsigned* __restrict__ gmax_u,
    const int* __restrict__ ep,
    int* __restrict__ ki, unsigned* __restrict__ thr_u, int* __restrict__ cless, int M)
{
    extern __shared__ unsigned keys[];      // M unsigned keys (68 KB for M=17408)
    int ax = blockIdx.x;
    int tid = threadIdx.x, lane = tid & 63, wv = tid >> 6;
    __shared__ int hist[256];
    __shared__ unsigned s_pref;
    __shared__ int s_kr, s_cl;
    __shared__ int wsum[4];

    if (tid == 0) {
        int c = *count;
        double cur = fmin(fmax((double)(ep[0] - 210), 0.0), 30.0);
        double r = 0.5 * (cos(PI_D * cur / 30.0) + 1.0);
        r = fmin(fmax(r, 0.8), 1.0);
        int k = (int)((double)c * r);    // truncation matches Python int()
        s_kr = k; s_pref = 0u; s_cl = 0;
        if (ax == 0) *ki = k;
    }

    // stage keys: independent loads, fully pipelined; one global pass total
    unsigned gmu = gmax_u[ax];
    const float* lb = lossbuf + (size_t)ax * M;
    for (int j = tid; j < M; j += 1024) {
        float t = tw[j];
        float l = lb[j];
        keys[j] = (t > 0.f) ? fflip(l) : gmu;
    }
    __syncthreads();

    int k0 = s_kr;
    if (k0 <= 0) { if (tid == 0) { thr_u[ax] = 0u; cless[ax] = 0; } return; }

    const unsigned mhi[4] = {0x00000000u, 0xFF000000u, 0xFFFF0000u, 0xFFFFFF00u};

    for (int pass = 0; pass < 4; ++pass) {
        int shift = 24 - 8 * pass;
        if (tid < 256) hist[tid] = 0;
        __syncthreads();
        unsigned m = mhi[pass];
        unsigned pref = s_pref;
        for (int j = tid; j < M; j += 1024) {
            unsigned v = keys[j];
            if ((v & m) == (pref & m)) atomicAdd(&hist[(v >> shift) & 255], 1);
        }
        __syncthreads();
        int kr = s_kr;                 // read before anyone can write it
        int h = (tid < 256) ? hist[tid] : 0;
        int inc = h;
        #pragma unroll
        for (int o = 1; o < 64; o <<= 1) {
            int n = __shfl_up(inc, o);
            if (lane >= o) inc += n;
        }
        if (lane == 63 && wv < 4) wsum[wv] = inc;
        __syncthreads();               // separates s_kr read from the write below
        if (tid < 256) {
            int off = 0;
            #pragma unroll
            for (int w = 0; w < 4; w++) if (w < wv) off += wsum[w];
            int incl = inc + off, excl = incl - h;
            if (excl < kr && incl >= kr) { // exactly one thread
                s_pref |= ((unsigned)tid) << shift;
                s_kr = kr - excl;
                s_cl += excl;
            }
        }
        __syncthreads();
    }
    if (tid == 0) { thr_u[ax] = s_pref; cless[ax] = s_cl; }
}

// ---------- kernel 4: weights + masked dot partials ----------
__global__ __launch_bounds__(256) void k_weight(
    const float* __restrict__ tw, const int* __restrict__ ul,
    const float* __restrict__ lossbuf, const unsigned* __restrict__ gmax_u,
    float* __restrict__ outw, const int* __restrict__ ki,
    const unsigned* __restrict__ thr_u, int* __restrict__ eqc,
    int* __restrict__ eqlist, double* __restrict__ acc, int M, int Kj)
{
    int ax = blockIdx.y;
    int m = blockIdx.x * blockDim.x + threadIdx.x;
    double contrib = 0.0;
    if (m < M) {
        int k = *ki;
        float mask = 0.f;
        unsigned v = (tw[m] > 0.f) ? fflip(lossbuf[(size_t)ax * M + m]) : gmax_u[ax];
        unsigned t = thr_u[ax];
        if (k > 0) {
            if (v < t) mask = 1.f;
            else if (v == t) {
                int pos = atomicAdd(&eqc[ax], 1);
                if (pos < EQCAP) eqlist[ax * EQCAP + pos] = m;
            }
        }
        float wr = (ul[m / Kj] == 0) ? tw[m] : 0.f;   // weight_real
        float wall = 2.f * wr + mask;
        outw[(size_t)ax * M + m] = wall;
        contrib = (double)lossbuf[(size_t)ax * M + m] * (double)wall;
    }
    #pragma unroll
    for (int o = 32; o; o >>= 1) contrib += __shfl_xor(contrib, o);
    __shared__ double s_c[4];
    int lane = threadIdx.x & 63, wv = threadIdx.x >> 6;
    if (lane == 0) s_c[wv] = contrib;
    __syncthreads();
    if (threadIdx.x == 0) atomicAdd(acc, s_c[0] + s_c[1] + s_c[2] + s_c[3]);
}

// ---------- kernel 5: tie fixup (lowest-index semantics) + final scalar ----------
__global__ __launch_bounds__(256) void k_fix(
    float* __restrict__ outw, float* __restrict__ out0,
    const float* __restrict__ lossbuf, const int* __restrict__ ki,
    const int* __restrict__ cless, const int* __restrict__ eqc,
    const int* __restrict__ eqlist, const double* __restrict__ acc, int M, int Kj)
{
    __shared__ double s_c[4];
    int tid = threadIdx.x;
    double extra = 0.0;
    for (int ax = 0; ax < 2; ++ax) {
        int k = *ki;
        int ec = eqc[ax]; if (ec > EQCAP) ec = EQCAP;
        int need = (k > 0) ? (k - cless[ax]) : 0;
        if (need < 0) need = 0;
        if (need > ec) need = ec;
        if (need == ec) {
            for (int i = tid; i < ec; i += 256) {
                int m = eqlist[ax * EQCAP + i];
                outw[(size_t)ax * M + m] += 1.f;
                extra += (double)lossbuf[(size_t)ax * M + m];
            }
        } else if (tid == 0) {
            // pick `need` lowest indices among equals (top_k tie semantics)
            int last = -1;
            for (int s = 0; s < need; ++s) {
                int best = 0x7fffffff;
                for (int i = 0; i < ec; i++) {
                    int v = eqlist[ax * EQCAP + i];
                    if (v > last && v < best) best = v;
                }
                last = best;
                outw[(size_t)ax * M + best] += 1.f;
                extra += (double)lossbuf[(size_t)ax * M + best];
            }
        }
        __syncthreads();
    }
    #pragma unroll
    for (int o = 32; o; o >>= 1) extra += __shfl_xor(extra, o);
    int lane = tid & 63, wv = tid >> 6;
    if (lane == 0) s_c[wv] = extra;
    __syncthreads();
    if (tid == 0)
        out0[0] = (float)((acc[0] + s_c[0] + s_c[1] + s_c[2] + s_c[3]) / (double)Kj);
}

extern "C" void kernel_launch(void* const* d_in, const int* in_sizes, int n_in,
                              void* d_out, int out_size, void* d_ws, size_t ws_size,
                              hipStream_t stream)
{
    const float* px = (const float*)d_in[0];
    const float* py = (const float*)d_in[1];
    const float* gx = (const float*)d_in[2];
    const float* gy = (const float*)d_in[3];
    const float* tw = (const float*)d_in[4];
    const int*   ul = (const int*)d_in[5];
    const int*   ep = (const int*)d_in[6];

    int M  = in_sizes[4];        // N*K = 17408
    int N  = in_sizes[5];        // 1024
    int Kj = M / N;              // 17

    float* out  = (float*)d_out;
    float* out0 = out;           // scalar loss
    float* outw = out + 1;       // [2*M] weights (x then y)

    char* ws = (char*)d_ws;
    double*   acc     = (double*)(ws + 0);
    int*      ki      = (int*)(ws + 8);
    int*      count   = (int*)(ws + 12);
    unsigned* gmax_u  = (unsigned*)(ws + 16);
    unsigned* thr_u   = (unsigned*)(ws + 24);
    int*      cless   = (int*)(ws + 32);
    int*      eqc     = (int*)(ws + 40);
    float*    lossbuf = (float*)(ws + 64);
    int*      eqlist  = (int*)(ws + 64 + (size_t)8 * M);

    k_init<<<1, 64, 0, stream>>>(acc, count, gmax_u, eqc);

    // per-row losses: one wave handles row m for BOTH axes (no atomics)
    int blocks = (M + 3) / 4;     // 4 waves (rows) per 256-thread block
    k_loss<<<blocks, 256, 0, stream>>>(px, py, gx, gy, lossbuf, M);

    // multi-block count + per-axis max (block-reduced atomics)
    k_stats2<<<(M + 255) / 256, 256, 0, stream>>>(tw, lossbuf, count, gmax_u, M);

    // radix select: stage keys in LDS (dynamic, M*4 bytes), 4 passes from LDS
    size_t lds_bytes = (size_t)M * sizeof(unsigned);
    k_select<<<2, 1024, lds_bytes, stream>>>(tw, lossbuf, count, gmax_u, ep,
                                             ki, thr_u, cless, M);

    // weights + dot partials
    dim3 g4((M + 255) / 256, 2);
    k_weight<<<g4, 256, 0, stream>>>(tw, ul, lossbuf, gmax_u, outw, ki, thr_u,
                                     eqc, eqlist, acc, M, Kj);

    // tie fixup + final scalar
    k_fix<<<1, 256, 0, stream>>>(outw, out0, lossbuf, ki, cless, eqc, eqlist, acc, M, Kj);
}